// Round 1
// baseline (3138.682 us; speedup 1.0000x reference)
//
#include <hip/hip_runtime.h>
#include <hip/hip_bf16.h>
#include <math.h>

// Model dims
#define DV   32000
#define DM   1024
#define DMLP 4096
#define DH   64
#define NH   16
#define NL   4
#define BATCH 2
#define S    2048
#define MTOK (BATCH*S)   // 4096 tokens
#define CH   8           // heads per attention chunk (scores buffer = CH*S*S bf16 = 67MB)

typedef __bf16 bf16_t;
typedef bf16_t bf16x8 __attribute__((ext_vector_type(8)));
typedef float  f32x4  __attribute__((ext_vector_type(4)));

// ---------------------------------------------------------------------------
// Generic TN GEMM: C[M,N] = A[M,K] * B[N,K]^T, bf16 in, f32 accum.
// MODE 0: write bf16 (optional bias/relu)
// MODE 1: write f32  (optional bias)
// MODE 2: residual add: resid_f32 += acc(+bias); residb_bf16 = bf16(resid)
// CAUSAL 0: none; 1: skip tiles with all keys > all queries (scores GEMM);
//        2: truncate K-loop at causal boundary (PV GEMM; masked P entries are 0)
// Requirements: M%BM==0, N%BN==0, K%32==0.
// ---------------------------------------------------------------------------
template<int BM, int BN, int MODE, bool BIAS, bool RELU, int CAUSAL>
__global__ __launch_bounds__(256)
void gemm_tn(const bf16_t* __restrict__ A, long sA,
             const bf16_t* __restrict__ Bm, long sB,
             char* __restrict__ Out, long sC, int ldc,
             const float* __restrict__ bias,
             float* __restrict__ resid, bf16_t* __restrict__ residb,
             int K)
{
    constexpr int BK = 32;
    constexpr int WM = BM/2, WN = BN/2;
    constexpr int FM = WM/16, FN = WN/16;

    const int mb = blockIdx.y, nb = blockIdx.x;
    if (CAUSAL == 1 && nb*BN >= mb*BM + BM) return;   // fully-masked tile

    __shared__ alignas(16) bf16_t As[BM*BK];
    __shared__ alignas(16) bf16_t Bs[BN*BK];

    const int tid  = threadIdx.x;
    const int wave = tid >> 6, lane = tid & 63;
    const int wm = wave >> 1, wn = wave & 1;
    const int l16 = lane & 15, lh = lane >> 4;
    const long z = blockIdx.z;

    const bf16_t* Ab = A  + z*sA + (long)mb*BM*K;
    const bf16_t* Bb = Bm + z*sB + (long)nb*BN*K;

    f32x4 acc[FM][FN];
#pragma unroll
    for (int i=0;i<FM;i++)
#pragma unroll
        for (int j=0;j<FN;j++) { f32x4 zv = {0.f,0.f,0.f,0.f}; acc[i][j] = zv; }

    int Kend = (CAUSAL == 2) ? ((mb+1)*BM < K ? (mb+1)*BM : K) : K;

    for (int k0 = 0; k0 < Kend; k0 += BK) {
        __syncthreads();
        // stage A tile [BM][BK] (linear row-major), coalesced 16B per thread
#pragma unroll
        for (int u=0; u<(BM*BK)/(256*8); ++u) {
            int t = u*256 + tid;
            int row = t >> 2, col = (t & 3)*8;
            *(bf16x8*)&As[t*8] = *(const bf16x8*)&Ab[(long)row*K + k0 + col];
        }
#pragma unroll
        for (int u=0; u<(BN*BK)/(256*8); ++u) {
            int t = u*256 + tid;
            int row = t >> 2, col = (t & 3)*8;
            *(bf16x8*)&Bs[t*8] = *(const bf16x8*)&Bb[(long)row*K + k0 + col];
        }
        __syncthreads();

        bf16x8 af[FM], bfr[FN];
#pragma unroll
        for (int i=0;i<FM;i++)
            af[i]  = *(const bf16x8*)&As[(wm*WM + i*16 + l16)*BK + lh*8];
#pragma unroll
        for (int j=0;j<FN;j++)
            bfr[j] = *(const bf16x8*)&Bs[(wn*WN + j*16 + l16)*BK + lh*8];
#pragma unroll
        for (int i=0;i<FM;i++)
#pragma unroll
            for (int j=0;j<FN;j++)
                acc[i][j] = __builtin_amdgcn_mfma_f32_16x16x32_bf16(af[i], bfr[j], acc[i][j], 0,0,0);
    }

    // epilogue: C/D layout col=lane&15, row=(lane>>4)*4+reg  [measured m89/m91]
#pragma unroll
    for (int i=0;i<FM;i++) {
        int row0 = mb*BM + wm*WM + i*16 + lh*4;
#pragma unroll
        for (int j=0;j<FN;j++) {
            int col = nb*BN + wn*WN + j*16 + l16;
            float bv = BIAS ? bias[col] : 0.0f;
#pragma unroll
            for (int r=0;r<4;r++) {
                int row = row0 + r;
                float v = acc[i][j][r] + bv;
                if (RELU) v = v > 0.f ? v : 0.f;
                if constexpr (MODE == 0) {
                    long off = z*sC + (long)row*ldc + col;
                    ((bf16_t*)Out)[off] = (bf16_t)v;
                } else if constexpr (MODE == 1) {
                    long off = z*sC + (long)row*ldc + col;
                    ((float*)Out)[off] = v;
                } else {
                    long o2 = (long)row*ldc + col;
                    float nv = resid[o2] + v;
                    resid[o2]  = nv;
                    residb[o2] = (bf16_t)nv;
                }
            }
        }
    }
}

// ---------------------------------------------------------------------------
// Weight conversion kernels
// ---------------------------------------------------------------------------
__global__ __launch_bounds__(256) void k_conv_qkv(
    const float* __restrict__ Wq, const float* __restrict__ Wk,
    const float* __restrict__ Wv, bf16_t* __restrict__ out)
{
    long idx = (long)blockIdx.x*256 + threadIdx.x;   // NL*3072*DM total
    long l = idx / (3072L*DM);
    long r = idx % (3072L*DM);
    int row = (int)(r / DM), d = (int)(r % DM);
    int sel = row >> 10, rr = row & 1023;
    const float* src = sel==0 ? Wq : (sel==1 ? Wk : Wv);
    out[idx] = (bf16_t)src[(l*1024 + rr)*(long)DM + d];
}

__global__ __launch_bounds__(256) void k_conv(const float* __restrict__ src,
                                              bf16_t* __restrict__ dst, long n)
{
    long i = ((long)blockIdx.x*256 + threadIdx.x)*4;
    if (i >= n) return;
    float4 v = *(const float4*)&src[i];
    dst[i+0]=(bf16_t)v.x; dst[i+1]=(bf16_t)v.y; dst[i+2]=(bf16_t)v.z; dst[i+3]=(bf16_t)v.w;
}

// W_U [DM][DV] -> WUt [DV][DM] bf16 (tiled transpose)
__global__ __launch_bounds__(256) void k_trans_wu(const float* __restrict__ W,
                                                  bf16_t* __restrict__ out)
{
    __shared__ float tile[32][33];
    int n0 = blockIdx.x*32, k0 = blockIdx.y*32;
    int tx = threadIdx.x & 31, ty = threadIdx.x >> 5;   // ty 0..7
#pragma unroll
    for (int u=0;u<4;u++)
        tile[ty+u*8][tx] = W[(long)(k0+ty+u*8)*DV + n0+tx];
    __syncthreads();
#pragma unroll
    for (int u=0;u<4;u++)
        out[(long)(n0+ty+u*8)*DM + k0+tx] = (bf16_t)tile[tx][ty+u*8];
}

// ---------------------------------------------------------------------------
// Embedding: x[b,p,d] = W_E[d, tok[b,p]] + W_pos[p,d]
// ---------------------------------------------------------------------------
__global__ __launch_bounds__(256) void k_embed(const int* __restrict__ tok,
    const float* __restrict__ WE, const float* __restrict__ Wpos,
    float* __restrict__ xf, bf16_t* __restrict__ xb)
{
    int bp = blockIdx.x;
    int p  = bp & (S-1);
    int t  = tok[bp];
#pragma unroll
    for (int u=0;u<4;u++) {
        int d = u*256 + threadIdx.x;
        float v = WE[(long)d*DV + t] + Wpos[(long)p*DM + d];
        xf[(long)bp*DM + d] = v;
        xb[(long)bp*DM + d] = (bf16_t)v;
    }
}

// qkv_flat [b,p,3072] -> q[b,h,p,dh], k[b,h,p,dh], vT[b,h,dh,p]
__global__ __launch_bounds__(256) void k_permute_qkv(const bf16_t* __restrict__ qkv,
    bf16_t* __restrict__ q, bf16_t* __restrict__ k, bf16_t* __restrict__ vt)
{
    long idx = (long)blockIdx.x*256 + threadIdx.x;    // MTOK*3072
    int n = (int)(idx % 3072);
    long bp = idx / 3072;
    int b = (int)(bp >> 11), p = (int)(bp & 2047);
    int sel = n >> 10, m = n & 1023;
    int i = m >> 6, hh = m & 63;
    bf16_t v = qkv[idx];
    long bh = (long)b*NH + i;
    if (sel == 0)      q[(bh*S + p)*DH + hh] = v;
    else if (sel == 1) k[(bh*S + p)*DH + hh] = v;
    else               vt[(bh*DH + hh)*S + p] = v;
}

// Masked, scaled, in-place softmax over key dim. One wave per query row.
// scores: [CH][S][S] bf16 for the current chunk.
__global__ __launch_bounds__(256) void k_softmax(bf16_t* __restrict__ scores)
{
    int rid  = blockIdx.x*4 + (threadIdx.x >> 6);
    int lane = threadIdx.x & 63;
    int z = rid >> 11, q = rid & 2047;
    bf16_t* row = scores + ((long)z*S + q)*S;
    const float scale = 0.125f;   // 1/sqrt(64)
    float vals[32];
    int k0 = lane*32;
    float m = -1e30f;
#pragma unroll
    for (int u=0;u<4;u++) {
        bf16x8 v8 = *(const bf16x8*)&row[k0 + u*8];
#pragma unroll
        for (int j=0;j<8;j++) {
            int k = k0 + u*8 + j;
            float s = (k <= q) ? (float)v8[j]*scale : -1e30f;
            vals[u*8+j] = s;
            m = fmaxf(m, s);
        }
    }
#pragma unroll
    for (int off=32; off; off>>=1) m = fmaxf(m, __shfl_xor(m, off));
    float sum = 0.f;
#pragma unroll
    for (int t=0;t<32;t++) { float e = __expf(vals[t]-m); vals[t]=e; sum += e; }
#pragma unroll
    for (int off=32; off; off>>=1) sum += __shfl_xor(sum, off);
    float rs = 1.0f/sum;
#pragma unroll
    for (int u=0;u<4;u++) {
        bf16x8 o;
#pragma unroll
        for (int j=0;j<8;j++) o[j] = (bf16_t)(vals[u*8+j]*rs);
        *(bf16x8*)&row[k0+u*8] = o;
    }
}

// ---------------------------------------------------------------------------
extern "C" void kernel_launch(void* const* d_in, const int* in_sizes, int n_in,
                              void* d_out, int out_size, void* d_ws, size_t ws_size,
                              hipStream_t stream)
{
    const int*   tokens = (const int*)d_in[0];
    const float* W_E    = (const float*)d_in[1];
    const float* W_pos  = (const float*)d_in[2];
    const float* W_K    = (const float*)d_in[3];
    const float* W_Q    = (const float*)d_in[4];
    const float* W_V    = (const float*)d_in[5];
    const float* W_O    = (const float*)d_in[6];
    const float* W_in   = (const float*)d_in[7];
    const float* b_in   = (const float*)d_in[8];
    const float* W_out  = (const float*)d_in[9];
    const float* b_out  = (const float*)d_in[10];
    const float* W_U    = (const float*)d_in[11];
    float* out = (float*)d_out;

    char* ws = (char*)d_ws;
    long off = 0;
    auto alloc = [&](long bytes)->char* {
        char* p = ws + off; off += (bytes + 255) & ~255L; return p;
    };
    bf16_t* wqkv = (bf16_t*)alloc((long)NL*3072*DM*2);
    bf16_t* wo   = (bf16_t*)alloc((long)NL*DM*DM*2);
    bf16_t* win  = (bf16_t*)alloc((long)NL*DMLP*DM*2);
    bf16_t* wout = (bf16_t*)alloc((long)NL*DM*DMLP*2);
    bf16_t* wut  = (bf16_t*)alloc((long)DV*DM*2);
    float*  xf   = (float*)alloc((long)MTOK*DM*4);
    bf16_t* xb   = (bf16_t*)alloc((long)MTOK*DM*2);
    bf16_t* qkvf = (bf16_t*)alloc((long)MTOK*3072*2);
    bf16_t* qb   = (bf16_t*)alloc((long)BATCH*NH*S*DH*2);
    bf16_t* kb   = (bf16_t*)alloc((long)BATCH*NH*S*DH*2);
    bf16_t* vt   = (bf16_t*)alloc((long)BATCH*NH*S*DH*2);
    bf16_t* zf   = (bf16_t*)alloc((long)MTOK*DM*2);
    bf16_t* post = (bf16_t*)alloc((long)MTOK*DMLP*2);
    bf16_t* sc   = (bf16_t*)alloc((long)CH*S*S*2);

    // --- weight conversion (per launch; deterministic) ---
    k_conv_qkv<<<(int)(((long)NL*3072*DM)/256), 256, 0, stream>>>(W_Q, W_K, W_V, wqkv);
    k_conv<<<(int)(((long)NL*DM*DM)/1024),   256, 0, stream>>>(W_O,   wo,   (long)NL*DM*DM);
    k_conv<<<(int)(((long)NL*DMLP*DM)/1024), 256, 0, stream>>>(W_in,  win,  (long)NL*DMLP*DM);
    k_conv<<<(int)(((long)NL*DM*DMLP)/1024), 256, 0, stream>>>(W_out, wout, (long)NL*DM*DMLP);
    k_trans_wu<<<dim3(DV/32, DM/32), 256, 0, stream>>>(W_U, wut);

    // --- embed ---
    k_embed<<<MTOK, 256, 0, stream>>>(tokens, W_E, W_pos, xf, xb);

    for (int l = 0; l < NL; ++l) {
        // QKV (fused N=3072)
        gemm_tn<128,128,0,false,false,0><<<dim3(3072/128, MTOK/128, 1), 256, 0, stream>>>(
            xb, 0L, wqkv + (long)l*3072*DM, 0L, (char*)qkvf, 0L, 3072,
            nullptr, nullptr, nullptr, DM);
        k_permute_qkv<<<(int)(((long)MTOK*3072)/256), 256, 0, stream>>>(qkvf, qb, kb, vt);

        for (int c = 0; c < (BATCH*NH)/CH; ++c) {
            int bh0 = c*CH;
            int b   = bh0 >> 4;
            int i0  = bh0 & 15;
            // scores[z][q][p] = Q[q,:]·K[p,:]
            gemm_tn<128,128,0,false,false,1><<<dim3(S/128, S/128, CH), 256, 0, stream>>>(
                qb + (long)bh0*S*DH, (long)S*DH,
                kb + (long)bh0*S*DH, (long)S*DH,
                (char*)sc, (long)S*S, S, nullptr, nullptr, nullptr, DH);
            k_softmax<<<(CH*S)/4, 256, 0, stream>>>(sc);
            // z[q][hh] = P[q,:]·V[:,hh], written straight into z_flat [b,q,(i,hh)]
            gemm_tn<128,64,0,false,false,2><<<dim3(1, S/128, CH), 256, 0, stream>>>(
                sc, (long)S*S,
                vt + (long)bh0*DH*S, (long)DH*S,
                (char*)(zf + (long)b*S*DM + (long)i0*DH), 64L, DM,
                nullptr, nullptr, nullptr, S);
        }

        // attn_out = z_flat @ W_O^T, fused residual add into x
        gemm_tn<128,128,2,false,false,0><<<dim3(DM/128, MTOK/128, 1), 256, 0, stream>>>(
            zf, 0L, wo + (long)l*DM*DM, 0L, nullptr, 0L, DM,
            nullptr, xf, xb, DM);
        // MLP in: relu(x @ W_in^T + b_in)
        gemm_tn<128,128,0,true,true,0><<<dim3(DMLP/128, MTOK/128, 1), 256, 0, stream>>>(
            xb, 0L, win + (long)l*DMLP*DM, 0L, (char*)post, 0L, DMLP,
            b_in + (long)l*DMLP, nullptr, nullptr, DM);
        // MLP out + b_out, fused residual add into x
        gemm_tn<128,128,2,true,false,0><<<dim3(DM/128, MTOK/128, 1), 256, 0, stream>>>(
            post, 0L, wout + (long)l*DM*DMLP, 0L, nullptr, 0L, DM,
            b_out + (long)l*DM, xf, xb, DMLP);
    }

    // logits = x @ W_U  (f32 out)
    gemm_tn<128,128,1,false,false,0><<<dim3(DV/128, MTOK/128, 1), 256, 0, stream>>>(
        xb, 0L, wut, 0L, (char*)out, 0L, DV,
        nullptr, nullptr, nullptr, DM);
}